// Round 1
// baseline (760.137 us; speedup 1.0000x reference)
//
#include <hip/hip_runtime.h>

// ---------------- problem constants ----------------
#define CCH   256
#define HH    96
#define WW    96
#define HO    94
#define LL    8836        // 94*94 patches
#define DD    2304        // 256*9
#define LPAD  8960        // 70 * 128
#define BM    128
#define BN    128
#define BK    32
#define NKT   (DD / BK)   // 72
#define NTI   (LPAD / BM) // 70

typedef unsigned short ushort_t;
typedef unsigned long long u64;

using short8 = __attribute__((ext_vector_type(8))) short;
using f32x4  = __attribute__((ext_vector_type(4))) float;

// ---------------- workspace layout (bytes) ----------------
// A bf16 [LPAD][DD]      :        0 .. 41,287,680
// B bf16 [LPAD][DD]      : 41287680 .. 82,575,360
// rnB  f32[LL]           : 82575360  (+35840)
// n2B  f32[LL]           : 82611200  (+35840)
// win2x f32[LL]          : 82647040  (+35840)
// P2   f32[2*9216]       : 82682880  (+73728)   [0..9215]=style, [9216..]=x
// best u64[LL]           : 82756608  (+71680)
#define OFF_B     41287680ull
#define OFF_RNB   82575360ull
#define OFF_N2B   82611200ull
#define OFF_W2X   82647040ull
#define OFF_P2    82682880ull
#define OFF_BEST  82756608ull

__device__ __forceinline__ ushort_t f2bf(float f) {
    unsigned u = __float_as_uint(f);
    unsigned r = (u + 0x7FFFu + ((u >> 16) & 1u)) >> 16;  // RNE
    return (ushort_t)r;
}

__device__ __forceinline__ void gload16(const ushort_t* g, ushort_t* l) {
    __builtin_amdgcn_global_load_lds(
        (const __attribute__((address_space(1))) unsigned int*)g,
        (__attribute__((address_space(3))) unsigned int*)l,
        16, 0, 0);
}

// ---- 1: per-pixel channel sum of squares for both images ----
__global__ __launch_bounds__(256) void k_chan_sumsq(const float* __restrict__ st,
                                                    const float* __restrict__ x,
                                                    float* __restrict__ P2) {
    int p = blockIdx.x * 256 + threadIdx.x;
    if (p >= 2 * HH * WW) return;
    const float* img = (p < HH * WW) ? st : x;
    int pp = (p < HH * WW) ? p : p - HH * WW;
    float s = 0.f;
#pragma unroll 4
    for (int c = 0; c < CCH; ++c) {
        float v = img[c * (HH * WW) + pp];
        s += v * v;
    }
    P2[p] = s;
}

// ---- 2: 3x3 window sums -> style inv-norms, style norm^2, x patch norm^2 ----
__global__ __launch_bounds__(256) void k_win(const float* __restrict__ P2,
                                             float* __restrict__ rnB,
                                             float* __restrict__ n2B,
                                             float* __restrict__ win2x) {
    int i = blockIdx.x * 256 + threadIdx.x;
    if (i >= LL) return;
    int y = i / HO, xc = i % HO;
    float ss = 0.f, sx = 0.f;
#pragma unroll
    for (int kh = 0; kh < 3; ++kh)
#pragma unroll
        for (int kw = 0; kw < 3; ++kw) {
            int off = (y + kh) * WW + xc + kw;
            ss += P2[off];
            sx += P2[HH * WW + off];
        }
    rnB[i] = 1.f / (sqrtf(ss) + 1e-8f);
    n2B[i] = ss;
    win2x[i] = sx;
}

// ---- 3: pack patches to bf16 [LPAD][DD]; A = raw x, B = normalized style ----
__global__ __launch_bounds__(256) void k_pack(const float* __restrict__ x,
                                              const float* __restrict__ st,
                                              const float* __restrict__ rnB,
                                              ushort_t* __restrict__ A,
                                              ushort_t* __restrict__ Bm) {
    int row = blockIdx.x;
    bool isB = row >= LPAD;
    int i = isB ? row - LPAD : row;
    ushort_t* dst = (isB ? Bm : A) + (size_t)i * DD + threadIdx.x * 9;
    if (i >= LL) {
#pragma unroll
        for (int k = 0; k < 9; ++k) dst[k] = 0;
        return;
    }
    int y = i / HO, xc = i % HO;
    const float* src = isB ? st : x;
    float scale = isB ? rnB[i] : 1.f;
    const float* base = src + (size_t)threadIdx.x * (HH * WW) + y * WW + xc;
#pragma unroll
    for (int kh = 0; kh < 3; ++kh)
#pragma unroll
        for (int kw = 0; kw < 3; ++kw)
            dst[kh * 3 + kw] = f2bf(base[kh * WW + kw] * scale);
}

// ---- 4: fused GEMM (A * B^T) + per-row argmax via packed atomicMax ----
__global__ __launch_bounds__(256) void k_gemm(const ushort_t* __restrict__ A,
                                              const ushort_t* __restrict__ Bm,
                                              u64* __restrict__ best) {
    __shared__ __align__(16) ushort_t As[BM * BK];   // 8 KB
    __shared__ __align__(16) ushort_t Bs[BN * BK];   // 8 KB

    const int bid = blockIdx.x;
    const int it = bid / NTI, jt = bid % NTI;
    const int t = threadIdx.x;
    const int wid = t >> 6, lane = t & 63;
    const int wr = wid >> 1, wc = wid & 1;
    const int l15 = lane & 15, l4 = lane >> 4;

    f32x4 acc[4][4];
#pragma unroll
    for (int mi = 0; mi < 4; ++mi)
#pragma unroll
        for (int ni = 0; ni < 4; ++ni)
            acc[mi][ni] = (f32x4){0.f, 0.f, 0.f, 0.f};

    const ushort_t* aptr = A  + (size_t)(it * BM + (t >> 2)) * DD + (t & 3) * 8;
    const ushort_t* bptr = Bm + (size_t)(jt * BN + (t >> 2)) * DD + (t & 3) * 8;

    for (int kt = 0; kt < NKT; ++kt) {
        const int k0 = kt * BK;
        gload16(aptr + k0,            &As[t * 8]);
        gload16(aptr + 64 * DD + k0,  &As[2048 + t * 8]);
        gload16(bptr + k0,            &Bs[t * 8]);
        gload16(bptr + 64 * DD + k0,  &Bs[2048 + t * 8]);
        __syncthreads();

        short8 af[4], bfr[4];
#pragma unroll
        for (int mi = 0; mi < 4; ++mi)
            af[mi] = *(const short8*)&As[(wr * 64 + mi * 16 + l15) * BK + l4 * 8];
#pragma unroll
        for (int ni = 0; ni < 4; ++ni)
            bfr[ni] = *(const short8*)&Bs[(wc * 64 + ni * 16 + l15) * BK + l4 * 8];
#pragma unroll
        for (int mi = 0; mi < 4; ++mi)
#pragma unroll
            for (int ni = 0; ni < 4; ++ni)
                acc[mi][ni] = __builtin_amdgcn_mfma_f32_16x16x32_bf16(
                    af[mi], bfr[ni], acc[mi][ni], 0, 0, 0);
        __syncthreads();
    }

    // epilogue: per output row, find max over this block's 128 j's, merge globally
    const int jbase = jt * BN + wc * 64 + l15;
#pragma unroll
    for (int mi = 0; mi < 4; ++mi) {
#pragma unroll
        for (int r = 0; r < 4; ++r) {
            float bv = -3.4e38f;
            int bj = 0x7FFFFFFF;
#pragma unroll
            for (int ni = 0; ni < 4; ++ni) {
                int j = jbase + ni * 16;
                float v = acc[mi][ni][r];
                if (j < LL && (v > bv || (v == bv && j < bj))) { bv = v; bj = j; }
            }
            // reduce across the 16 lanes holding the same row (lane bits 0..3)
#pragma unroll
            for (int m = 1; m < 16; m <<= 1) {
                float ov = __shfl_xor(bv, m, 64);
                int oj = __shfl_xor(bj, m, 64);
                if (ov > bv || (ov == bv && oj < bj)) { bv = ov; bj = oj; }
            }
            if (l15 == 0) {
                int i = it * BM + wr * 64 + mi * 16 + l4 * 4 + r;
                if (i < LL) {
                    unsigned u = __float_as_uint(bv);
                    unsigned s = (bv < 0.f) ? ~u : (u | 0x80000000u);
                    u64 packed = ((u64)s << 32) | (unsigned)(~(unsigned)bj);
                    atomicMax(&best[i], packed);
                }
            }
        }
    }
}

// ---- 5: final scalar: sum_i [ ||ip_i||^2 + ||sp_j*||^2 - 2*dot ] / (D*L) ----
__global__ __launch_bounds__(256) void k_final(const u64* __restrict__ best,
                                               const float* __restrict__ rnB,
                                               const float* __restrict__ n2B,
                                               const float* __restrict__ win2x,
                                               float* __restrict__ out) {
    int i = blockIdx.x * 256 + threadIdx.x;
    float contrib = 0.f;
    if (i < LL) {
        u64 p = best[i];
        unsigned s = (unsigned)(p >> 32);
        unsigned ub = (s & 0x80000000u) ? (s & 0x7FFFFFFFu) : ~s;
        float bv = __uint_as_float(ub);
        int j = (int)(~(unsigned)(p & 0xFFFFFFFFull));
        float dot = bv / rnB[j];                  // ip_i . sp_j  (bv = ip_i . spn_j)
        contrib = win2x[i] + n2B[j] - 2.f * dot;
    }
    // block reduction
    float sred = contrib;
#pragma unroll
    for (int o = 32; o > 0; o >>= 1) sred += __shfl_down(sred, o, 64);
    __shared__ float red[4];
    if ((threadIdx.x & 63) == 0) red[threadIdx.x >> 6] = sred;
    __syncthreads();
    if (threadIdx.x == 0) {
        float tot = red[0] + red[1] + red[2] + red[3];
        atomicAdd(out, tot * (1.0f / ((float)DD * (float)LL)));
    }
}

extern "C" void kernel_launch(void* const* d_in, const int* in_sizes, int n_in,
                              void* d_out, int out_size, void* d_ws, size_t ws_size,
                              hipStream_t stream) {
    const float* x  = (const float*)d_in[0];
    const float* st = (const float*)d_in[1];
    char* ws = (char*)d_ws;

    ushort_t* A    = (ushort_t*)ws;
    ushort_t* Bm   = (ushort_t*)(ws + OFF_B);
    float* rnB     = (float*)(ws + OFF_RNB);
    float* n2B     = (float*)(ws + OFF_N2B);
    float* win2x   = (float*)(ws + OFF_W2X);
    float* P2      = (float*)(ws + OFF_P2);
    u64* best      = (u64*)(ws + OFF_BEST);
    float* out     = (float*)d_out;

    hipMemsetAsync(best, 0, (size_t)LL * 8, stream);
    hipMemsetAsync(out, 0, sizeof(float), stream);

    k_chan_sumsq<<<dim3(72), dim3(256), 0, stream>>>(st, x, P2);
    k_win<<<dim3(35), dim3(256), 0, stream>>>(P2, rnB, n2B, win2x);
    k_pack<<<dim3(2 * LPAD), dim3(256), 0, stream>>>(x, st, rnB, A, Bm);
    k_gemm<<<dim3(NTI * NTI), dim3(256), 0, stream>>>(A, Bm, best);
    k_final<<<dim3(35), dim3(256), 0, stream>>>(best, rnB, n2B, win2x, out);
}

// Round 2
// 541.391 us; speedup vs baseline: 1.4040x; 1.4040x over previous
//
#include <hip/hip_runtime.h>

// ---------------- problem constants ----------------
#define CCH   256
#define HH    96
#define WW    96
#define HO    94
#define LL    8836        // 94*94 patches
#define DD    2304        // 256*9
#define LPAD  8960        // 35 * 256

// GEMM2 geometry: 256x256 tile, BK=32, 8 waves (2M x 4N), 512 threads
#define BM2   256
#define BK2   32
#define NK2   72          // 2304/32
#define NT2   35          // 8960/256
#define SLOT_ELE 16384    // 32 KB per ring slot (A 16KB + B 16KB) in ushorts
#define BOFF_ELE 8192     // B region offset within slot (elements)

typedef unsigned short ushort_t;
typedef unsigned long long u64;

using short8 = __attribute__((ext_vector_type(8))) short;
using f32x4  = __attribute__((ext_vector_type(4))) float;

// ---------------- workspace layout (bytes) ----------------
#define OFF_B     41287680ull
#define OFF_RNB   82575360ull
#define OFF_N2B   82611200ull
#define OFF_W2X   82647040ull
#define OFF_P2    82682880ull
#define OFF_BEST  82756608ull

__device__ __forceinline__ ushort_t f2bf(float f) {
    unsigned u = __float_as_uint(f);
    unsigned r = (u + 0x7FFFu + ((u >> 16) & 1u)) >> 16;  // RNE
    return (ushort_t)r;
}

__device__ __forceinline__ void gload16(const ushort_t* g, ushort_t* l) {
    __builtin_amdgcn_global_load_lds(
        (const __attribute__((address_space(1))) unsigned int*)g,
        (__attribute__((address_space(3))) unsigned int*)l,
        16, 0, 0);
}

// ---- 1: per-pixel channel sum of squares for both images ----
__global__ __launch_bounds__(256) void k_chan_sumsq(const float* __restrict__ st,
                                                    const float* __restrict__ x,
                                                    float* __restrict__ P2) {
    int p = blockIdx.x * 256 + threadIdx.x;
    if (p >= 2 * HH * WW) return;
    const float* img = (p < HH * WW) ? st : x;
    int pp = (p < HH * WW) ? p : p - HH * WW;
    float s = 0.f;
#pragma unroll 4
    for (int c = 0; c < CCH; ++c) {
        float v = img[c * (HH * WW) + pp];
        s += v * v;
    }
    P2[p] = s;
}

// ---- 2: 3x3 window sums -> style inv-norms, style norm^2, x patch norm^2 ----
__global__ __launch_bounds__(256) void k_win(const float* __restrict__ P2,
                                             float* __restrict__ rnB,
                                             float* __restrict__ n2B,
                                             float* __restrict__ win2x) {
    int i = blockIdx.x * 256 + threadIdx.x;
    if (i >= LL) return;
    int y = i / HO, xc = i % HO;
    float ss = 0.f, sx = 0.f;
#pragma unroll
    for (int kh = 0; kh < 3; ++kh)
#pragma unroll
        for (int kw = 0; kw < 3; ++kw) {
            int off = (y + kh) * WW + xc + kw;
            ss += P2[off];
            sx += P2[HH * WW + off];
        }
    rnB[i] = 1.f / (sqrtf(ss) + 1e-8f);
    n2B[i] = ss;
    win2x[i] = sx;
}

// ---- 3: pack patches to bf16 [LPAD][DD]; A = raw x, B = normalized style ----
__global__ __launch_bounds__(256) void k_pack(const float* __restrict__ x,
                                              const float* __restrict__ st,
                                              const float* __restrict__ rnB,
                                              ushort_t* __restrict__ A,
                                              ushort_t* __restrict__ Bm) {
    int row = blockIdx.x;
    bool isB = row >= LPAD;
    int i = isB ? row - LPAD : row;
    ushort_t* dst = (isB ? Bm : A) + (size_t)i * DD + threadIdx.x * 9;
    if (i >= LL) {
#pragma unroll
        for (int k = 0; k < 9; ++k) dst[k] = 0;
        return;
    }
    int y = i / HO, xc = i % HO;
    const float* src = isB ? st : x;
    float scale = isB ? rnB[i] : 1.f;
    const float* base = src + (size_t)threadIdx.x * (HH * WW) + y * WW + xc;
#pragma unroll
    for (int kh = 0; kh < 3; ++kh)
#pragma unroll
        for (int kw = 0; kw < 3; ++kw)
            dst[kh * 3 + kw] = f2bf(base[kh * WW + kw] * scale);
}

// ---- 4: fused GEMM (A * B^T) + per-row argmax, 256^2 phase-split schedule ----
__global__ __launch_bounds__(512, 2) void k_gemm2(const ushort_t* __restrict__ A,
                                                  const ushort_t* __restrict__ Bm,
                                                  u64* __restrict__ best) {
    extern __shared__ __align__(16) ushort_t lds[];  // 4 slots x 32 KB = 128 KiB

    const int t = threadIdx.x;
    const int wid = t >> 6, lane = t & 63;
    const int wr = wid >> 2, wc = wid & 3;
    const int l15 = lane & 15, l4 = lane >> 4;

    // T1: bijective XCD swizzle (m204), nwg = 1225
    const int nwg = NT2 * NT2;
    const int q = nwg >> 3, r = nwg & 7;  // 153, 1
    const int bid = blockIdx.x;
    const int xcd = bid & 7, loc = bid >> 3;
    const int swz = ((xcd < r) ? xcd * (q + 1) : r * (q + 1) + (xcd - r) * q) + loc;
    const int it = swz / NT2, jt = swz % NT2;

    // staging source pointers (pre-swizzled k-slice: ksl = (t&3) ^ ((t>>3)&3))
    const int ksl = (t & 3) ^ ((t >> 3) & 3);
    const ushort_t* asrc0 = A  + (size_t)(it * BM2 + (t >> 2)) * DD + ksl * 8;
    const ushort_t* asrc1 = asrc0 + (size_t)128 * DD;
    const ushort_t* bsrc0 = Bm + (size_t)(jt * BM2 + (t >> 2)) * DD + ksl * 8;
    const ushort_t* bsrc1 = bsrc0 + (size_t)128 * DD;
    const int ldst = t * 8;  // element offset within a half region (lane*16 B)

    // fragment read offsets (swizzled): slot ^= (row>>1)&3  ->  sp8 element offset
    const int sp8 = (l4 ^ ((l15 >> 1) & 3)) * 8;
    int aoffs[8], boffs[4];
#pragma unroll
    for (int mi = 0; mi < 8; ++mi)
        aoffs[mi] = (wr * 128 + mi * 16 + l15) * BK2 + sp8;
#pragma unroll
    for (int ni = 0; ni < 4; ++ni)
        boffs[ni] = BOFF_ELE + (wc * 64 + ni * 16 + l15) * BK2 + sp8;

    f32x4 acc[8][4];
#pragma unroll
    for (int mi = 0; mi < 8; ++mi)
#pragma unroll
        for (int ni = 0; ni < 4; ++ni)
            acc[mi][ni] = (f32x4){0.f, 0.f, 0.f, 0.f};

#define STAGE_A(kt, slot)                                                        \
    do {                                                                         \
        gload16(asrc0 + (kt) * BK2, lds + (slot) * SLOT_ELE + ldst);             \
        gload16(asrc1 + (kt) * BK2, lds + (slot) * SLOT_ELE + 4096 + ldst);      \
    } while (0)
#define STAGE_B(kt, slot)                                                        \
    do {                                                                         \
        gload16(bsrc0 + (kt) * BK2, lds + (slot) * SLOT_ELE + BOFF_ELE + ldst);  \
        gload16(bsrc1 + (kt) * BK2, lds + (slot) * SLOT_ELE + BOFF_ELE + 4096 + ldst); \
    } while (0)

    // prologue: stage K-tiles 0 and 1; wait for tile 0 (leave tile 1's 4 loads in flight)
    STAGE_A(0, 0); STAGE_B(0, 0);
    STAGE_A(1, 1); STAGE_B(1, 1);
    asm volatile("s_waitcnt vmcnt(4)" ::: "memory");
    __builtin_amdgcn_sched_barrier(0);
    __builtin_amdgcn_s_barrier();

    short8 af[4], bfr[4];
    for (int kt = 0; kt < NK2; ++kt) {
        const ushort_t* sbase = lds + (kt & 3) * SLOT_ELE;
        const int pslot = (kt + 2) & 3;
        // ---- phase 0: read B(0-3) + A(0-3); stage A of kt+2 ----
#pragma unroll
        for (int ni = 0; ni < 4; ++ni) bfr[ni] = *(const short8*)(sbase + boffs[ni]);
#pragma unroll
        for (int mi = 0; mi < 4; ++mi) af[mi] = *(const short8*)(sbase + aoffs[mi]);
        STAGE_A(kt + 2, pslot);
        __builtin_amdgcn_s_barrier();
        asm volatile("s_waitcnt lgkmcnt(0)" ::: "memory");
        __builtin_amdgcn_sched_barrier(0);
        __builtin_amdgcn_s_setprio(1);
#pragma unroll
        for (int mi = 0; mi < 4; ++mi)
#pragma unroll
            for (int ni = 0; ni < 4; ++ni)
                acc[mi][ni] = __builtin_amdgcn_mfma_f32_16x16x32_bf16(
                    af[mi], bfr[ni], acc[mi][ni], 0, 0, 0);
        __builtin_amdgcn_s_setprio(0);
        __builtin_amdgcn_s_barrier();
        // ---- phase 1: read A(4-7); stage B of kt+2 ----
#pragma unroll
        for (int mi = 0; mi < 4; ++mi) af[mi] = *(const short8*)(sbase + aoffs[4 + mi]);
        STAGE_B(kt + 2, pslot);
        __builtin_amdgcn_s_barrier();
        asm volatile("s_waitcnt lgkmcnt(0)" ::: "memory");
        __builtin_amdgcn_sched_barrier(0);
        __builtin_amdgcn_s_setprio(1);
#pragma unroll
        for (int mi = 0; mi < 4; ++mi)
#pragma unroll
            for (int ni = 0; ni < 4; ++ni)
                acc[4 + mi][ni] = __builtin_amdgcn_mfma_f32_16x16x32_bf16(
                    af[mi], bfr[ni], acc[4 + mi][ni], 0, 0, 0);
        __builtin_amdgcn_s_setprio(0);
        // counted vmcnt: keep only kt+2's 4 stage loads in flight (never 0)
        asm volatile("s_waitcnt vmcnt(4)" ::: "memory");
        __builtin_amdgcn_sched_barrier(0);
        __builtin_amdgcn_s_barrier();
    }
#undef STAGE_A
#undef STAGE_B

    // epilogue: per output row, max over this block's 256 j's, merge globally
    const int jbase = jt * BM2 + wc * 64 + l15;
#pragma unroll
    for (int mi = 0; mi < 8; ++mi) {
#pragma unroll
        for (int rr = 0; rr < 4; ++rr) {
            float bv = -3.4e38f;
            int bj = 0x7FFFFFFF;
#pragma unroll
            for (int ni = 0; ni < 4; ++ni) {
                int j = jbase + ni * 16;
                float v = acc[mi][ni][rr];
                if (j < LL && (v > bv || (v == bv && j < bj))) { bv = v; bj = j; }
            }
#pragma unroll
            for (int m = 1; m < 16; m <<= 1) {
                float ov = __shfl_xor(bv, m, 64);
                int oj = __shfl_xor(bj, m, 64);
                if (ov > bv || (ov == bv && oj < bj)) { bv = ov; bj = oj; }
            }
            if (l15 == 0) {
                int i = it * BM2 + wr * 128 + mi * 16 + l4 * 4 + rr;
                if (i < LL) {
                    unsigned u = __float_as_uint(bv);
                    unsigned s = (bv < 0.f) ? ~u : (u | 0x80000000u);
                    u64 packed = ((u64)s << 32) | (unsigned)(~(unsigned)bj);
                    atomicMax(&best[i], packed);
                }
            }
        }
    }
}

// ---- 5: final scalar ----
__global__ __launch_bounds__(256) void k_final(const u64* __restrict__ best,
                                               const float* __restrict__ rnB,
                                               const float* __restrict__ n2B,
                                               const float* __restrict__ win2x,
                                               float* __restrict__ out) {
    int i = blockIdx.x * 256 + threadIdx.x;
    float contrib = 0.f;
    if (i < LL) {
        u64 p = best[i];
        unsigned s = (unsigned)(p >> 32);
        unsigned ub = (s & 0x80000000u) ? (s & 0x7FFFFFFFu) : ~s;
        float bv = __uint_as_float(ub);
        int j = (int)(~(unsigned)(p & 0xFFFFFFFFull));
        float dot = bv / rnB[j];
        contrib = win2x[i] + n2B[j] - 2.f * dot;
    }
    float sred = contrib;
#pragma unroll
    for (int o = 32; o > 0; o >>= 1) sred += __shfl_down(sred, o, 64);
    __shared__ float red[4];
    if ((threadIdx.x & 63) == 0) red[threadIdx.x >> 6] = sred;
    __syncthreads();
    if (threadIdx.x == 0) {
        float tot = red[0] + red[1] + red[2] + red[3];
        atomicAdd(out, tot * (1.0f / ((float)DD * (float)LL)));
    }
}

extern "C" void kernel_launch(void* const* d_in, const int* in_sizes, int n_in,
                              void* d_out, int out_size, void* d_ws, size_t ws_size,
                              hipStream_t stream) {
    const float* x  = (const float*)d_in[0];
    const float* st = (const float*)d_in[1];
    char* ws = (char*)d_ws;

    ushort_t* A    = (ushort_t*)ws;
    ushort_t* Bm   = (ushort_t*)(ws + OFF_B);
    float* rnB     = (float*)(ws + OFF_RNB);
    float* n2B     = (float*)(ws + OFF_N2B);
    float* win2x   = (float*)(ws + OFF_W2X);
    float* P2      = (float*)(ws + OFF_P2);
    u64* best      = (u64*)(ws + OFF_BEST);
    float* out     = (float*)d_out;

    // allow 128 KiB dynamic LDS for k_gemm2 (idempotent, non-stream op)
    hipFuncSetAttribute((const void*)k_gemm2,
                        hipFuncAttributeMaxDynamicSharedMemorySize, 131072);

    hipMemsetAsync(best, 0, (size_t)LL * 8, stream);
    hipMemsetAsync(out, 0, sizeof(float), stream);

    k_chan_sumsq<<<dim3(72), dim3(256), 0, stream>>>(st, x, P2);
    k_win<<<dim3(35), dim3(256), 0, stream>>>(P2, rnB, n2B, win2x);
    k_pack<<<dim3(2 * LPAD), dim3(256), 0, stream>>>(x, st, rnB, A, Bm);
    k_gemm2<<<dim3(NT2 * NT2), dim3(512), 131072, stream>>>(A, Bm, best);
    k_final<<<dim3(35), dim3(256), 0, stream>>>(best, rnB, n2B, win2x, out);
}

// Round 3
// 512.888 us; speedup vs baseline: 1.4821x; 1.0556x over previous
//
#include <hip/hip_runtime.h>

// ---------------- problem constants ----------------
#define CCH   256
#define HH    96
#define WW    96
#define HO    94
#define LL    8836        // 94*94 patches
#define DD    2304        // 256*9
#define LPAD  8960        // 35 * 256

// GEMM geometry: 256x256 tile, BK=32, 8 waves (2M x 4N), 512 threads
#define BM2   256
#define BK2   32
#define NK2   72          // 2304/32
#define NT2   35          // 8960/256
#define SLOT_ELE 16384    // 32 KB per ring slot (A 16KB + B 16KB) in ushorts
#define BOFF_ELE 8192     // B region offset within slot (elements)

typedef unsigned short ushort_t;
typedef unsigned long long u64;

using short8 = __attribute__((ext_vector_type(8))) short;
using f32x4  = __attribute__((ext_vector_type(4))) float;

// ---------------- workspace layout (bytes) ----------------
#define OFF_B     41287680ull
#define OFF_RNB   82575360ull
#define OFF_N2B   82611200ull
#define OFF_W2X   82647040ull
#define OFF_P2    82682880ull
#define OFF_BEST  82756608ull

__device__ __forceinline__ ushort_t f2bf(float f) {
    unsigned u = __float_as_uint(f);
    unsigned r = (u + 0x7FFFu + ((u >> 16) & 1u)) >> 16;  // RNE
    return (ushort_t)r;
}

__device__ __forceinline__ void gload16(const ushort_t* g, ushort_t* l) {
    __builtin_amdgcn_global_load_lds(
        (const __attribute__((address_space(1))) unsigned int*)g,
        (__attribute__((address_space(3))) unsigned int*)l,
        16, 0, 0);
}

// ---- 1: per-pixel channel sum of squares for both images ----
__global__ __launch_bounds__(256) void k_chan_sumsq(const float* __restrict__ st,
                                                    const float* __restrict__ x,
                                                    float* __restrict__ P2) {
    int p = blockIdx.x * 256 + threadIdx.x;
    if (p >= 2 * HH * WW) return;
    const float* img = (p < HH * WW) ? st : x;
    int pp = (p < HH * WW) ? p : p - HH * WW;
    float s = 0.f;
#pragma unroll 4
    for (int c = 0; c < CCH; ++c) {
        float v = img[c * (HH * WW) + pp];
        s += v * v;
    }
    P2[p] = s;
}

// ---- 2: 3x3 window sums -> style inv-norms, style norm^2, x patch norm^2 ----
__global__ __launch_bounds__(256) void k_win(const float* __restrict__ P2,
                                             float* __restrict__ rnB,
                                             float* __restrict__ n2B,
                                             float* __restrict__ win2x) {
    int i = blockIdx.x * 256 + threadIdx.x;
    if (i >= LL) return;
    int y = i / HO, xc = i % HO;
    float ss = 0.f, sx = 0.f;
#pragma unroll
    for (int kh = 0; kh < 3; ++kh)
#pragma unroll
        for (int kw = 0; kw < 3; ++kw) {
            int off = (y + kh) * WW + xc + kw;
            ss += P2[off];
            sx += P2[HH * WW + off];
        }
    rnB[i] = 1.f / (sqrtf(ss) + 1e-8f);
    n2B[i] = ss;
    win2x[i] = sx;
}

// ---- 3: pack patches to bf16 [LPAD][DD]; A = raw x, B = normalized style ----
__global__ __launch_bounds__(256) void k_pack(const float* __restrict__ x,
                                              const float* __restrict__ st,
                                              const float* __restrict__ rnB,
                                              ushort_t* __restrict__ A,
                                              ushort_t* __restrict__ Bm) {
    int row = blockIdx.x;
    bool isB = row >= LPAD;
    int i = isB ? row - LPAD : row;
    ushort_t* dst = (isB ? Bm : A) + (size_t)i * DD + threadIdx.x * 9;
    if (i >= LL) {
#pragma unroll
        for (int k = 0; k < 9; ++k) dst[k] = 0;
        return;
    }
    int y = i / HO, xc = i % HO;
    const float* src = isB ? st : x;
    float scale = isB ? rnB[i] : 1.f;
    const float* base = src + (size_t)threadIdx.x * (HH * WW) + y * WW + xc;
#pragma unroll
    for (int kh = 0; kh < 3; ++kh)
#pragma unroll
        for (int kw = 0; kw < 3; ++kw)
            dst[kh * 3 + kw] = f2bf(base[kh * WW + kw] * scale);
}

// ---- 4: fused GEMM (A * B^T) + per-row argmax, read-ahead pipelined phases ----
__global__ __launch_bounds__(512, 2) void k_gemm2(const ushort_t* __restrict__ A,
                                                  const ushort_t* __restrict__ Bm,
                                                  u64* __restrict__ best) {
    extern __shared__ __align__(16) ushort_t lds[];  // 4 slots x 32 KB = 128 KiB

    const int t = threadIdx.x;
    const int wid = t >> 6, lane = t & 63;
    const int wr = wid >> 2, wc = wid & 3;
    const int l15 = lane & 15, l4 = lane >> 4;

    // T1: bijective XCD swizzle (m204), nwg = 1225
    const int nwg = NT2 * NT2;
    const int q = nwg >> 3, r = nwg & 7;  // 153, 1
    const int bid = blockIdx.x;
    const int xcd = bid & 7, loc = bid >> 3;
    const int swz = ((xcd < r) ? xcd * (q + 1) : r * (q + 1) + (xcd - r) * q) + loc;
    const int it = swz / NT2, jt = swz % NT2;

    // staging source pointers (pre-swizzled k-slice: ksl = (t&3) ^ ((t>>3)&3))
    const int ksl = (t & 3) ^ ((t >> 3) & 3);
    const ushort_t* asrc0 = A  + (size_t)(it * BM2 + (t >> 2)) * DD + ksl * 8;
    const ushort_t* asrc1 = asrc0 + (size_t)128 * DD;
    const ushort_t* bsrc0 = Bm + (size_t)(jt * BM2 + (t >> 2)) * DD + ksl * 8;
    const ushort_t* bsrc1 = bsrc0 + (size_t)128 * DD;
    const int ldst = t * 8;  // element offset within a half region (lane*16 B)

    // fragment read offsets (swizzled): slot ^= (row>>1)&3 -> sp8 element offset
    const int sp8 = (l4 ^ ((l15 >> 1) & 3)) * 8;
    int aoff[8], boff[4];
#pragma unroll
    for (int mi = 0; mi < 8; ++mi)
        aoff[mi] = (wr * 128 + mi * 16 + l15) * BK2 + sp8;
#pragma unroll
    for (int ni = 0; ni < 4; ++ni)
        boff[ni] = BOFF_ELE + (wc * 64 + ni * 16 + l15) * BK2 + sp8;

    f32x4 acc[8][4];
#pragma unroll
    for (int mi = 0; mi < 8; ++mi)
#pragma unroll
        for (int ni = 0; ni < 4; ++ni)
            acc[mi][ni] = (f32x4){0.f, 0.f, 0.f, 0.f};

#define STAGE_A(KT, SLOT)                                                        \
    do {                                                                         \
        gload16(asrc0 + (KT) * BK2, lds + (SLOT) * SLOT_ELE + ldst);             \
        gload16(asrc1 + (KT) * BK2, lds + (SLOT) * SLOT_ELE + 4096 + ldst);      \
    } while (0)
#define STAGE_B(KT, SLOT)                                                        \
    do {                                                                         \
        gload16(bsrc0 + (KT) * BK2, lds + (SLOT) * SLOT_ELE + BOFF_ELE + ldst);  \
        gload16(bsrc1 + (KT) * BK2, lds + (SLOT) * SLOT_ELE + BOFF_ELE + 4096 + ldst); \
    } while (0)

    short8 af03[4], af47[4], bfrA[4], bfrB[4];

    // prologue: stage K-tiles 0 and 1; wait tile 0+1... (vmcnt(4): tile0 landed)
    STAGE_A(0, 0); STAGE_B(0, 0);
    STAGE_A(1, 1); STAGE_B(1, 1);
    asm volatile("s_waitcnt vmcnt(4)" ::: "memory");
    __builtin_amdgcn_sched_barrier(0);
    __builtin_amdgcn_s_barrier();
    // pre-read fragments for K-tile 0 (slot 0): bfr(0) + af03(0) -> 8 ds_reads
#pragma unroll
    for (int ni = 0; ni < 4; ++ni) bfrA[ni] = *(const short8*)(lds + boff[ni]);
#pragma unroll
    for (int mi = 0; mi < 4; ++mi) af03[mi] = *(const short8*)(lds + aoff[mi]);

// One K-tile: phase A (MFMA half0, pre-read af47, stage A(kt+2), vmcnt+barrier)
//             phase B (MFMA half1, pre-read bfr/af03 of kt+1, stage B(kt+2))
#define ITER(KT, BCUR, BNXT)                                                     \
    {                                                                            \
        const ushort_t* baseA = lds + ((KT) & 3) * SLOT_ELE;                     \
        const ushort_t* baseB = lds + (((KT) + 1) & 3) * SLOT_ELE;               \
        const int sP = ((KT) + 2) & 3;                                           \
        /* ---- phase A ---- */                                                  \
        _Pragma("unroll")                                                        \
        for (int mi = 0; mi < 4; ++mi)                                           \
            af47[mi] = *(const short8*)(baseA + aoff[4 + mi]);                   \
        STAGE_A((KT) + 2, sP);                                                   \
        asm volatile("s_waitcnt vmcnt(2)" ::: "memory");                         \
        __builtin_amdgcn_sched_barrier(0);                                       \
        __builtin_amdgcn_s_barrier();                                            \
        asm volatile("s_waitcnt lgkmcnt(4)" ::: "memory");                       \
        __builtin_amdgcn_sched_barrier(0);                                       \
        __builtin_amdgcn_s_setprio(1);                                           \
        _Pragma("unroll")                                                        \
        for (int mi = 0; mi < 4; ++mi)                                           \
            _Pragma("unroll")                                                    \
            for (int ni = 0; ni < 4; ++ni)                                       \
                acc[mi][ni] = __builtin_amdgcn_mfma_f32_16x16x32_bf16(           \
                    af03[mi], BCUR[ni], acc[mi][ni], 0, 0, 0);                   \
        __builtin_amdgcn_s_setprio(0);                                           \
        /* ---- phase B ---- */                                                  \
        _Pragma("unroll")                                                        \
        for (int ni = 0; ni < 4; ++ni)                                           \
            BNXT[ni] = *(const short8*)(baseB + boff[ni]);                       \
        _Pragma("unroll")                                                        \
        for (int mi = 0; mi < 4; ++mi)                                           \
            af03[mi] = *(const short8*)(baseB + aoff[mi]);                       \
        STAGE_B((KT) + 2, sP);                                                   \
        __builtin_amdgcn_s_barrier();                                            \
        asm volatile("s_waitcnt lgkmcnt(8)" ::: "memory");                       \
        __builtin_amdgcn_sched_barrier(0);                                       \
        __builtin_amdgcn_s_setprio(1);                                           \
        _Pragma("unroll")                                                        \
        for (int mi = 0; mi < 4; ++mi)                                           \
            _Pragma("unroll")                                                    \
            for (int ni = 0; ni < 4; ++ni)                                       \
                acc[4 + mi][ni] = __builtin_amdgcn_mfma_f32_16x16x32_bf16(       \
                    af47[mi], BCUR[ni], acc[4 + mi][ni], 0, 0, 0);               \
        __builtin_amdgcn_s_setprio(0);                                           \
    }

    for (int kt2 = 0; kt2 < NK2; kt2 += 2) {
        ITER(kt2,     bfrA, bfrB);
        ITER(kt2 + 1, bfrB, bfrA);
    }
#undef ITER
#undef STAGE_A
#undef STAGE_B

    // epilogue: per output row, max over this block's 256 j's, merge globally
    const int jbase = jt * BM2 + wc * 64 + l15;
#pragma unroll
    for (int mi = 0; mi < 8; ++mi) {
#pragma unroll
        for (int rr = 0; rr < 4; ++rr) {
            float bv = -3.4e38f;
            int bj = 0x7FFFFFFF;
#pragma unroll
            for (int ni = 0; ni < 4; ++ni) {
                int j = jbase + ni * 16;
                float v = acc[mi][ni][rr];
                if (j < LL && (v > bv || (v == bv && j < bj))) { bv = v; bj = j; }
            }
#pragma unroll
            for (int m = 1; m < 16; m <<= 1) {
                float ov = __shfl_xor(bv, m, 64);
                int oj = __shfl_xor(bj, m, 64);
                if (ov > bv || (ov == bv && oj < bj)) { bv = ov; bj = oj; }
            }
            if (l15 == 0) {
                int i = it * BM2 + wr * 128 + mi * 16 + l4 * 4 + rr;
                if (i < LL) {
                    unsigned u = __float_as_uint(bv);
                    unsigned s = (bv < 0.f) ? ~u : (u | 0x80000000u);
                    u64 packed = ((u64)s << 32) | (unsigned)(~(unsigned)bj);
                    atomicMax(&best[i], packed);
                }
            }
        }
    }
}

// ---- 5: final scalar ----
__global__ __launch_bounds__(256) void k_final(const u64* __restrict__ best,
                                               const float* __restrict__ rnB,
                                               const float* __restrict__ n2B,
                                               const float* __restrict__ win2x,
                                               float* __restrict__ out) {
    int i = blockIdx.x * 256 + threadIdx.x;
    float contrib = 0.f;
    if (i < LL) {
        u64 p = best[i];
        unsigned s = (unsigned)(p >> 32);
        unsigned ub = (s & 0x80000000u) ? (s & 0x7FFFFFFFu) : ~s;
        float bv = __uint_as_float(ub);
        int j = (int)(~(unsigned)(p & 0xFFFFFFFFull));
        float dot = bv / rnB[j];
        contrib = win2x[i] + n2B[j] - 2.f * dot;
    }
    float sred = contrib;
#pragma unroll
    for (int o = 32; o > 0; o >>= 1) sred += __shfl_down(sred, o, 64);
    __shared__ float red[4];
    if ((threadIdx.x & 63) == 0) red[threadIdx.x >> 6] = sred;
    __syncthreads();
    if (threadIdx.x == 0) {
        float tot = red[0] + red[1] + red[2] + red[3];
        atomicAdd(out, tot * (1.0f / ((float)DD * (float)LL)));
    }
}

extern "C" void kernel_launch(void* const* d_in, const int* in_sizes, int n_in,
                              void* d_out, int out_size, void* d_ws, size_t ws_size,
                              hipStream_t stream) {
    const float* x  = (const float*)d_in[0];
    const float* st = (const float*)d_in[1];
    char* ws = (char*)d_ws;

    ushort_t* A    = (ushort_t*)ws;
    ushort_t* Bm   = (ushort_t*)(ws + OFF_B);
    float* rnB     = (float*)(ws + OFF_RNB);
    float* n2B     = (float*)(ws + OFF_N2B);
    float* win2x   = (float*)(ws + OFF_W2X);
    float* P2      = (float*)(ws + OFF_P2);
    u64* best      = (u64*)(ws + OFF_BEST);
    float* out     = (float*)d_out;

    hipFuncSetAttribute((const void*)k_gemm2,
                        hipFuncAttributeMaxDynamicSharedMemorySize, 131072);

    hipMemsetAsync(best, 0, (size_t)LL * 8, stream);
    hipMemsetAsync(out, 0, sizeof(float), stream);

    k_chan_sumsq<<<dim3(72), dim3(256), 0, stream>>>(st, x, P2);
    k_win<<<dim3(35), dim3(256), 0, stream>>>(P2, rnB, n2B, win2x);
    k_pack<<<dim3(2 * LPAD), dim3(256), 0, stream>>>(x, st, rnB, A, Bm);
    k_gemm2<<<dim3(NT2 * NT2), dim3(512), 131072, stream>>>(A, Bm, best);
    k_final<<<dim3(35), dim3(256), 0, stream>>>(best, rnB, n2B, win2x, out);
}